// Round 5
// baseline (14001.465 us; speedup 1.0000x reference)
//
#include <hip/hip_runtime.h>
#include <hip/hip_bf16.h>

#define S_LEN 4096
#define IDIM  2048
#define HDIM  2048
#define G4    8192
#define NB    256
#define TPB   512
#define SENT  0x7FC00000u   // qNaN: h = sigmoid*tanh products are never NaN

typedef __attribute__((ext_vector_type(2))) float  f32x2;
typedef __attribute__((ext_vector_type(4))) float  f32x4;
typedef __attribute__((ext_vector_type(8))) short  bf16x8;

// packed fp32 FMA: acc = w*h + acc (2 MACs/instruction, CDNA dual fp32 pipe)
#define PKFMA(acc, w, h) \
  asm("v_pk_fma_f32 %0, %1, %2, %0" : "+v"(acc) : "v"(w), "v"(h))

// ---- bf16 helpers ----
__device__ __forceinline__ unsigned short f2bf(float f) {
  unsigned u = __float_as_uint(f);
  unsigned r = (u + 0x7FFFu + ((u >> 16) & 1u)) >> 16;   // RNE
  return (unsigned short)r;
}
__device__ __forceinline__ float bf2f(unsigned short h) {
  return __uint_as_float(((unsigned)h) << 16);
}

// =====================================================================
// Kernel 0: fill out with sentinel (readiness = "word != SENT").
// Agent-scope stores so the pattern is visible to sc1 polls immediately.
// =====================================================================
__global__ __launch_bounds__(256) void fill_sentinel(unsigned long long* p) {
  const unsigned long long v =
      ((unsigned long long)SENT << 32) | (unsigned long long)SENT;
  const int n = S_LEN * HDIM / 2;
  for (int i = blockIdx.x * 256 + threadIdx.x; i < n; i += gridDim.x * 256)
    __hip_atomic_store(p + i, v, __ATOMIC_RELAXED, __HIP_MEMORY_SCOPE_AGENT);
}

// =====================================================================
// Kernel 1: xg = x·W_ihᵀ + b_ih + b_hh, bf16 MFMA. (proven, ~0.1 ms)
// =====================================================================
#define BM 128
#define BKK 32
#define LDK 40

__global__ __launch_bounds__(256) void gemm_xg_mfma(
    const float* __restrict__ x, const float* __restrict__ Wih,
    const float* __restrict__ bih, const float* __restrict__ bhh,
    unsigned short* __restrict__ xg) {
  __shared__ unsigned short As[BM][LDK];
  __shared__ unsigned short Bs[BM][LDK];

  const int t = threadIdx.x;
  const int lane = t & 63, wid = t >> 6;
  const int wr = wid >> 1, wc = wid & 1;

  int bid = ((int)blockIdx.x & 7) * 256 + ((int)blockIdx.x >> 3);
  const int s0 = (bid >> 6) * BM;
  const int j0 = (bid & 63) * BM;

  f32x4 acc[4][4] = {};

  float bias[4];
#pragma unroll
  for (int n = 0; n < 4; ++n) {
    const int col = j0 + wc * 64 + n * 16 + (lane & 15);
    bias[n] = bih[col] + bhh[col];
  }

  for (int k0 = 0; k0 < IDIM; k0 += BKK) {
    float4 va[4], vb[4];
#pragma unroll
    for (int u = 0; u < 4; ++u) {
      const int f = t + 256 * u;
      const int row = f >> 3, kc = (f & 7) * 4;
      va[u] = *(const float4*)&x  [(size_t)(s0 + row) * IDIM + k0 + kc];
      vb[u] = *(const float4*)&Wih[(size_t)(j0 + row) * IDIM + k0 + kc];
    }
    __syncthreads();
#pragma unroll
    for (int u = 0; u < 4; ++u) {
      const int f = t + 256 * u;
      const int row = f >> 3, kc = (f & 7) * 4;
      ushort4 pa, pb;
      pa.x = f2bf(va[u].x); pa.y = f2bf(va[u].y);
      pa.z = f2bf(va[u].z); pa.w = f2bf(va[u].w);
      pb.x = f2bf(vb[u].x); pb.y = f2bf(vb[u].y);
      pb.z = f2bf(vb[u].z); pb.w = f2bf(vb[u].w);
      *(ushort4*)&As[row][kc] = pa;
      *(ushort4*)&Bs[row][kc] = pb;
    }
    __syncthreads();

    const int fr = lane & 15, koff = (lane >> 4) * 8;
    bf16x8 a[4], bfr[4];
#pragma unroll
    for (int m = 0; m < 4; ++m)
      a[m] = *(const bf16x8*)&As[wr * 64 + m * 16 + fr][koff];
#pragma unroll
    for (int n = 0; n < 4; ++n)
      bfr[n] = *(const bf16x8*)&Bs[wc * 64 + n * 16 + fr][koff];
#pragma unroll
    for (int m = 0; m < 4; ++m)
#pragma unroll
      for (int n = 0; n < 4; ++n)
        acc[m][n] = __builtin_amdgcn_mfma_f32_16x16x32_bf16(
            a[m], bfr[n], acc[m][n], 0, 0, 0);
  }

#pragma unroll
  for (int m = 0; m < 4; ++m) {
    const int row0 = s0 + wr * 64 + m * 16 + (lane >> 4) * 4;
#pragma unroll
    for (int n = 0; n < 4; ++n) {
      const int col = j0 + wc * 64 + n * 16 + (lane & 15);
#pragma unroll
      for (int r = 0; r < 4; ++r)
        xg[(size_t)(row0 + r) * G4 + col] = f2bf(acc[m][n][r] + bias[n]);
    }
  }
}

// =====================================================================
// Kernel 2: persistent scan — sentinel sync (readiness == data, 1 RT).
//  publish: lane0 of wave w stores h (4B relaxed agent atomic) straight
//           into out[ts]. No flag, no barrier, no tag.
//  acquire: thread t polls out[ts-1] words {2t,2t+1,2t+1024,2t+1025}
//           via 2x8B sc1 loads until != SENT; stage to LDS; 1 barrier.
//  Single h_sh buffer is safe: passing poll(ts+1) implies all blocks
//  published ts, which implies this block's waves finished reading h_sh.
//  Dot uses v_pk_fma_f32, interleaved k-map (lane l: k = 4l + 256i + d):
//  conflict-free ds_read_b128, coalesced one-time weight loads.
// =====================================================================
__global__ __launch_bounds__(TPB, 2) void lstm_scan(
    const unsigned short* __restrict__ xg, const float* __restrict__ Whh,
    const float* __restrict__ h0, const float* __restrict__ c0,
    float* __restrict__ out) {
  __shared__ __align__(16) float h_sh[HDIM];

  const int b = blockIdx.x, t = threadIdx.x;
  const int lane = t & 63, wid = t >> 6;
  const int j = b * 8 + wid;                      // this wave's unit

  // weights: gate g, lane l covers k in {4l + 256i + d : i<8, d<4}
  f32x2 w2[4][16];
#pragma unroll
  for (int g = 0; g < 4; ++g) {
    const float* wp = Whh + ((size_t)g * HDIM + j) * HDIM + lane * 4;
#pragma unroll
    for (int i = 0; i < 8; ++i) {
      const float4 v = *(const float4*)(wp + i * 256);
      w2[g][i * 2 + 0] = f32x2{v.x, v.y};
      w2[g][i * 2 + 1] = f32x2{v.z, v.w};
    }
  }
  float c_reg = (lane == 0) ? c0[j] : 0.f;

  for (int ts = 0; ts < S_LEN; ++ts) {
    // xg prefetch (lanes 0-3: this unit's 4 gate pre-activations)
    float xgv = 0.f;
    if (lane < 4)
      xgv = bf2f(xg[(size_t)ts * G4 + (size_t)lane * HDIM + j]);

    if (ts == 0) {
      h_sh[2*t]        = h0[2*t];
      h_sh[2*t + 1]    = h0[2*t + 1];
      h_sh[2*t + 1024] = h0[2*t + 1024];
      h_sh[2*t + 1025] = h0[2*t + 1025];
    } else {
      const unsigned long long* src =
          (const unsigned long long*)(out + (size_t)(ts - 1) * HDIM);
      unsigned long long r0 = 0, r1 = 0;
      int d0 = 0, d1 = 0;
      for (;;) {
        if (!d0) {
          r0 = __hip_atomic_load(src + t, __ATOMIC_RELAXED,
                                 __HIP_MEMORY_SCOPE_AGENT);
          d0 = ((unsigned)r0 != SENT) & ((unsigned)(r0 >> 32) != SENT);
        }
        if (!d1) {
          r1 = __hip_atomic_load(src + t + 512, __ATOMIC_RELAXED,
                                 __HIP_MEMORY_SCOPE_AGENT);
          d1 = ((unsigned)r1 != SENT) & ((unsigned)(r1 >> 32) != SENT);
        }
        if (d0 & d1) break;
        __builtin_amdgcn_s_sleep(1);
      }
      h_sh[2*t]        = __uint_as_float((unsigned)r0);
      h_sh[2*t + 1]    = __uint_as_float((unsigned)(r0 >> 32));
      h_sh[2*t + 1024] = __uint_as_float((unsigned)r1);
      h_sh[2*t + 1025] = __uint_as_float((unsigned)(r1 >> 32));
    }
    __syncthreads();                               // only barrier per step

    // ---- packed dot: 64 v_pk_fma_f32 vs conflict-free LDS reads ----
    f32x2 A0 = {0.f, 0.f}, A1 = {0.f, 0.f}, A2 = {0.f, 0.f}, A3 = {0.f, 0.f};
    const f32x4* h4 = (const f32x4*)&h_sh[lane * 4];
#pragma unroll
    for (int i = 0; i < 8; ++i) {
      const f32x4 hv = h4[i * 64];                 // dw 4*lane + 256*i
      const f32x2 hlo = {hv.x, hv.y}, hhi = {hv.z, hv.w};
      PKFMA(A0, w2[0][i*2+0], hlo); PKFMA(A0, w2[0][i*2+1], hhi);
      PKFMA(A1, w2[1][i*2+0], hlo); PKFMA(A1, w2[1][i*2+1], hhi);
      PKFMA(A2, w2[2][i*2+0], hlo); PKFMA(A2, w2[2][i*2+1], hhi);
      PKFMA(A3, w2[3][i*2+0], hlo); PKFMA(A3, w2[3][i*2+1], hhi);
    }
    float a0 = A0.x + A0.y, a1 = A1.x + A1.y;
    float a2 = A2.x + A2.y, a3 = A3.x + A3.y;
#pragma unroll
    for (int m = 1; m < 64; m <<= 1) {
      a0 += __shfl_xor(a0, m);
      a1 += __shfl_xor(a1, m);
      a2 += __shfl_xor(a2, m);
      a3 += __shfl_xor(a3, m);
    }
    // lanes 0-3: activation of gate 'lane'
    float sv = (lane == 0) ? a0 : (lane == 1) ? a1 : (lane == 2) ? a2 : a3;
    sv += xgv;
    const float av = (lane == 2) ? tanhf(sv) : 1.f / (1.f + __expf(-sv));
    const float iv = __shfl(av, 0);
    const float fv = __shfl(av, 1);
    const float gv = __shfl(av, 2);
    const float ov = __shfl(av, 3);
    if (lane == 0) {
      c_reg = fmaf(fv, c_reg, iv * gv);
      const float hn = ov * tanhf(c_reg);
      // the publication IS the output write (single 4B store, 1 RT)
      __hip_atomic_store(&out[(size_t)ts * HDIM + j], hn,
                         __ATOMIC_RELAXED, __HIP_MEMORY_SCOPE_AGENT);
    }
    // no trailing barrier; next-step poll gates reuse of h_sh
  }
}

// =====================================================================
extern "C" void kernel_launch(void* const* d_in, const int* in_sizes, int n_in,
                              void* d_out, int out_size, void* d_ws, size_t ws_size,
                              hipStream_t stream) {
  const float* x   = (const float*)d_in[0];
  const float* Wih = (const float*)d_in[1];
  const float* Whh = (const float*)d_in[2];
  const float* bih = (const float*)d_in[3];
  const float* bhh = (const float*)d_in[4];
  const float* h0  = (const float*)d_in[5];
  const float* c0  = (const float*)d_in[6];
  float* out = (float*)d_out;

  unsigned short* xg = (unsigned short*)d_ws;       // 64 MB bf16

  // 1) sentinel-fill out (readiness protocol ground state)
  fill_sentinel<<<dim3(2048), 256, 0, stream>>>((unsigned long long*)out);
  // 2) input-gate GEMM
  gemm_xg_mfma<<<dim3(2048), 256, 0, stream>>>(x, Wih, bih, bhh, xg);
  // 3) persistent scan
  void* args[] = {(void*)&xg, (void*)&Whh, (void*)&h0, (void*)&c0, (void*)&out};
  hipLaunchCooperativeKernel((void*)lstm_scan, dim3(NB), dim3(TPB),
                             args, 0, stream);
}

// Round 6
// 12227.154 us; speedup vs baseline: 1.1451x; 1.1451x over previous
//
#include <hip/hip_runtime.h>
#include <hip/hip_bf16.h>

#define S_LEN 4096
#define IDIM  2048
#define HDIM  2048
#define G4    8192
#define NB    256
#define TPB   512
#define SENT  0x7FC00000u   // qNaN: h = sigmoid*tanh of finite data, never NaN

typedef __attribute__((ext_vector_type(2))) float  f32x2;
typedef __attribute__((ext_vector_type(4))) float  f32x4;
typedef __attribute__((ext_vector_type(8))) short  bf16x8;

// packed fp32 FMA: acc = w*h + acc (2 MACs/instruction)
#define PKFMA(acc, w, h) \
  asm("v_pk_fma_f32 %0, %1, %2, %0" : "+v"(acc) : "v"(w), "v"(h))

// ---- bf16 helpers ----
__device__ __forceinline__ unsigned short f2bf(float f) {
  unsigned u = __float_as_uint(f);
  unsigned r = (u + 0x7FFFu + ((u >> 16) & 1u)) >> 16;   // RNE
  return (unsigned short)r;
}
__device__ __forceinline__ float bf2f(unsigned short h) {
  return __uint_as_float(((unsigned)h) << 16);
}
// fast activations (v_exp + v_rcp; ~1e-6 rel err, well under bf16 margin)
__device__ __forceinline__ float sigmoid_fast(float x) {
  return __builtin_amdgcn_rcpf(1.f + __expf(-x));
}
__device__ __forceinline__ float tanh_fast(float x) {
  return 1.f - 2.f * __builtin_amdgcn_rcpf(__expf(2.f * x) + 1.f);
}

// =====================================================================
// Kernel 0: fill out with sentinel (per-element readiness ground state)
// =====================================================================
__global__ __launch_bounds__(256) void fill_sentinel(unsigned long long* p) {
  const unsigned long long v =
      ((unsigned long long)SENT << 32) | (unsigned long long)SENT;
  const int n = S_LEN * HDIM / 2;
  for (int i = blockIdx.x * 256 + threadIdx.x; i < n; i += gridDim.x * 256)
    p[i] = v;   // kernel-boundary release makes this agent-visible
}

// =====================================================================
// Kernel 1: xg = x·W_ihᵀ + b_ih + b_hh, bf16 MFMA. (proven, ~0.1 ms)
// =====================================================================
#define BM 128
#define BKK 32
#define LDK 40

__global__ __launch_bounds__(256) void gemm_xg_mfma(
    const float* __restrict__ x, const float* __restrict__ Wih,
    const float* __restrict__ bih, const float* __restrict__ bhh,
    unsigned short* __restrict__ xg) {
  __shared__ unsigned short As[BM][LDK];
  __shared__ unsigned short Bs[BM][LDK];

  const int t = threadIdx.x;
  const int lane = t & 63, wid = t >> 6;
  const int wr = wid >> 1, wc = wid & 1;

  int bid = ((int)blockIdx.x & 7) * 256 + ((int)blockIdx.x >> 3);
  const int s0 = (bid >> 6) * BM;
  const int j0 = (bid & 63) * BM;

  f32x4 acc[4][4] = {};

  float bias[4];
#pragma unroll
  for (int n = 0; n < 4; ++n) {
    const int col = j0 + wc * 64 + n * 16 + (lane & 15);
    bias[n] = bih[col] + bhh[col];
  }

  for (int k0 = 0; k0 < IDIM; k0 += BKK) {
    float4 va[4], vb[4];
#pragma unroll
    for (int u = 0; u < 4; ++u) {
      const int f = t + 256 * u;
      const int row = f >> 3, kc = (f & 7) * 4;
      va[u] = *(const float4*)&x  [(size_t)(s0 + row) * IDIM + k0 + kc];
      vb[u] = *(const float4*)&Wih[(size_t)(j0 + row) * IDIM + k0 + kc];
    }
    __syncthreads();
#pragma unroll
    for (int u = 0; u < 4; ++u) {
      const int f = t + 256 * u;
      const int row = f >> 3, kc = (f & 7) * 4;
      ushort4 pa, pb;
      pa.x = f2bf(va[u].x); pa.y = f2bf(va[u].y);
      pa.z = f2bf(va[u].z); pa.w = f2bf(va[u].w);
      pb.x = f2bf(vb[u].x); pb.y = f2bf(vb[u].y);
      pb.z = f2bf(vb[u].z); pb.w = f2bf(vb[u].w);
      *(ushort4*)&As[row][kc] = pa;
      *(ushort4*)&Bs[row][kc] = pb;
    }
    __syncthreads();

    const int fr = lane & 15, koff = (lane >> 4) * 8;
    bf16x8 a[4], bfr[4];
#pragma unroll
    for (int m = 0; m < 4; ++m)
      a[m] = *(const bf16x8*)&As[wr * 64 + m * 16 + fr][koff];
#pragma unroll
    for (int n = 0; n < 4; ++n)
      bfr[n] = *(const bf16x8*)&Bs[wc * 64 + n * 16 + fr][koff];
#pragma unroll
    for (int m = 0; m < 4; ++m)
#pragma unroll
      for (int n = 0; n < 4; ++n)
        acc[m][n] = __builtin_amdgcn_mfma_f32_16x16x32_bf16(
            a[m], bfr[n], acc[m][n], 0, 0, 0);
  }

#pragma unroll
  for (int m = 0; m < 4; ++m) {
    const int row0 = s0 + wr * 64 + m * 16 + (lane >> 4) * 4;
#pragma unroll
    for (int n = 0; n < 4; ++n) {
      const int col = j0 + wc * 64 + n * 16 + (lane & 15);
#pragma unroll
      for (int r = 0; r < 4; ++r)
        xg[(size_t)(row0 + r) * G4 + col] = f2bf(acc[m][n][r] + bias[n]);
    }
  }
}

// =====================================================================
// Kernel 2: persistent scan — hint-flags + sentinel-verified bulk read.
//  publish: lane0 stores h (4B relaxed agent) into out[ts]; raw s_barrier
//           (NO vmcnt drain — no store-ack wait); t0 stores flags[b]=ts+1.
//  acquire: wave0 polls the 1KB flag array (tiny footprint — the r3/r5
//           lesson: distributed data-polling overloads the LLC); barrier;
//           all threads bulk-read out[ts-1] with PER-ELEMENT sentinel
//           retry (flags are only a hint; correctness is per-element).
//  h_sh reuse gated by BAR1 (all waves past their dot before next stage).
// =====================================================================
__global__ __launch_bounds__(TPB, 2) void lstm_scan(
    const unsigned short* __restrict__ xg, const float* __restrict__ Whh,
    const float* __restrict__ h0, const float* __restrict__ c0,
    float* __restrict__ out, unsigned* __restrict__ flags) {
  __shared__ __align__(16) float h_sh[HDIM];

  const int b = blockIdx.x, t = threadIdx.x;
  const int lane = t & 63, wid = t >> 6;
  const int j = b * 8 + wid;                      // this wave's unit

  // weights: gate g, lane l covers k in {4l + 256i + d : i<8, d<4}
  f32x2 w2[4][16];
#pragma unroll
  for (int g = 0; g < 4; ++g) {
    const float* wp = Whh + ((size_t)g * HDIM + j) * HDIM + lane * 4;
#pragma unroll
    for (int i = 0; i < 8; ++i) {
      const float4 v = *(const float4*)(wp + i * 256);
      w2[g][i * 2 + 0] = f32x2{v.x, v.y};
      w2[g][i * 2 + 1] = f32x2{v.z, v.w};
    }
  }
  float c_reg = (lane == 0) ? c0[j] : 0.f;

  for (int ts = 0; ts < S_LEN; ++ts) {
    // xg prefetch (lanes 0-3: this unit's 4 gate pre-activations)
    float xgv = 0.f;
    if (lane < 4)
      xgv = bf2f(xg[(size_t)ts * G4 + (size_t)lane * HDIM + j]);

    if (ts == 0) {
      __syncthreads();                             // BAR1 (uniform count)
      h_sh[2*t]        = h0[2*t];
      h_sh[2*t + 1]    = h0[2*t + 1];
      h_sh[2*t + 1024] = h0[2*t + 1024];
      h_sh[2*t + 1025] = h0[2*t + 1025];
    } else {
      // ---- wave0: poll 256 hint-flags (1 KB; reload only missing) ----
      if (wid == 0) {
        const unsigned want = (unsigned)ts;
        unsigned f0 = 0, f1 = 0, f2 = 0, f3 = 0;
        for (;;) {
          if (f0 < want) f0 = __hip_atomic_load(&flags[lane],       __ATOMIC_RELAXED, __HIP_MEMORY_SCOPE_AGENT);
          if (f1 < want) f1 = __hip_atomic_load(&flags[lane +  64], __ATOMIC_RELAXED, __HIP_MEMORY_SCOPE_AGENT);
          if (f2 < want) f2 = __hip_atomic_load(&flags[lane + 128], __ATOMIC_RELAXED, __HIP_MEMORY_SCOPE_AGENT);
          if (f3 < want) f3 = __hip_atomic_load(&flags[lane + 192], __ATOMIC_RELAXED, __HIP_MEMORY_SCOPE_AGENT);
          if (f0 >= want && f1 >= want && f2 >= want && f3 >= want) break;
          __builtin_amdgcn_s_sleep(1);
        }
      }
      __syncthreads();                             // BAR1: hint seen; h_sh free
      // ---- bulk read h_{ts-1}: 2x8B/thread, per-element sentinel retry ----
      const unsigned long long* src =
          (const unsigned long long*)(out + (size_t)(ts - 1) * HDIM);
      unsigned long long r0, r1;
      do {
        r0 = __hip_atomic_load(src + t, __ATOMIC_RELAXED,
                               __HIP_MEMORY_SCOPE_AGENT);
      } while (((unsigned)r0 == SENT) | ((unsigned)(r0 >> 32) == SENT));
      do {
        r1 = __hip_atomic_load(src + t + 512, __ATOMIC_RELAXED,
                               __HIP_MEMORY_SCOPE_AGENT);
      } while (((unsigned)r1 == SENT) | ((unsigned)(r1 >> 32) == SENT));
      h_sh[2*t]        = __uint_as_float((unsigned)r0);
      h_sh[2*t + 1]    = __uint_as_float((unsigned)(r0 >> 32));
      h_sh[2*t + 1024] = __uint_as_float((unsigned)r1);
      h_sh[2*t + 1025] = __uint_as_float((unsigned)(r1 >> 32));
    }
    __syncthreads();                               // BAR2: h_sh ready

    // ---- packed dot: 64 v_pk_fma_f32 vs conflict-free b128 LDS reads ----
    f32x2 A0 = {0.f, 0.f}, A1 = {0.f, 0.f}, A2 = {0.f, 0.f}, A3 = {0.f, 0.f};
    const f32x4* h4 = (const f32x4*)&h_sh[lane * 4];
#pragma unroll
    for (int i = 0; i < 8; ++i) {
      const f32x4 hv = h4[i * 64];                 // dw 4*lane + 256*i
      const f32x2 hlo = {hv.x, hv.y}, hhi = {hv.z, hv.w};
      PKFMA(A0, w2[0][i*2+0], hlo); PKFMA(A0, w2[0][i*2+1], hhi);
      PKFMA(A1, w2[1][i*2+0], hlo); PKFMA(A1, w2[1][i*2+1], hhi);
      PKFMA(A2, w2[2][i*2+0], hlo); PKFMA(A2, w2[2][i*2+1], hhi);
      PKFMA(A3, w2[3][i*2+0], hlo); PKFMA(A3, w2[3][i*2+1], hhi);
    }
    float a0 = A0.x + A0.y, a1 = A1.x + A1.y;
    float a2 = A2.x + A2.y, a3 = A3.x + A3.y;
#pragma unroll
    for (int m = 1; m < 64; m <<= 1) {
      a0 += __shfl_xor(a0, m);
      a1 += __shfl_xor(a1, m);
      a2 += __shfl_xor(a2, m);
      a3 += __shfl_xor(a3, m);
    }
    // lanes 0-3: activation of gate 'lane'
    float sv = (lane == 0) ? a0 : (lane == 1) ? a1 : (lane == 2) ? a2 : a3;
    sv += xgv;
    const float av = (lane == 2) ? tanh_fast(sv) : sigmoid_fast(sv);
    const float iv = __shfl(av, 0);
    const float fv = __shfl(av, 1);
    const float gv = __shfl(av, 2);
    const float ov = __shfl(av, 3);
    if (lane == 0) {
      c_reg = fmaf(fv, c_reg, iv * gv);
      const float hn = ov * tanh_fast(c_reg);
      __hip_atomic_store(&out[(size_t)ts * HDIM + j], hn,
                         __ATOMIC_RELAXED, __HIP_MEMORY_SCOPE_AGENT);
    }
    // raw barrier: collect all 8 waves' store-ISSUE points; no vmcnt drain
    // (no store-ack RT on the critical path — sentinel retry is the backstop)
    asm volatile("" ::: "memory");
    __builtin_amdgcn_s_barrier();
    asm volatile("" ::: "memory");
    if (t == 0)
      __hip_atomic_store(&flags[b], (unsigned)(ts + 1),
                         __ATOMIC_RELAXED, __HIP_MEMORY_SCOPE_AGENT);
  }
}

// =====================================================================
extern "C" void kernel_launch(void* const* d_in, const int* in_sizes, int n_in,
                              void* d_out, int out_size, void* d_ws, size_t ws_size,
                              hipStream_t stream) {
  const float* x   = (const float*)d_in[0];
  const float* Wih = (const float*)d_in[1];
  const float* Whh = (const float*)d_in[2];
  const float* bih = (const float*)d_in[3];
  const float* bhh = (const float*)d_in[4];
  const float* h0  = (const float*)d_in[5];
  const float* c0  = (const float*)d_in[6];
  float* out = (float*)d_out;

  // ws layout: [0,1KB) flags | [32KB, +64MB) xg bf16
  unsigned* flags = (unsigned*)d_ws;
  unsigned short* xg = (unsigned short*)((char*)d_ws + 32768);

  hipMemsetAsync(flags, 0, NB * sizeof(unsigned), stream);

  fill_sentinel<<<dim3(2048), 256, 0, stream>>>((unsigned long long*)out);
  gemm_xg_mfma<<<dim3(2048), 256, 0, stream>>>(x, Wih, bih, bhh, xg);

  void* args[] = {(void*)&xg, (void*)&Whh, (void*)&h0,
                  (void*)&c0, (void*)&out, (void*)&flags};
  hipLaunchCooperativeKernel((void*)lstm_scan, dim3(NB), dim3(TPB),
                             args, 0, stream);
}